// Round 3
// baseline (497.652 us; speedup 1.0000x reference)
//
#include <hip/hip_runtime.h>

// 2-layer LSTM (H=64) encode(128) + AR(60), B=4096, persistent per-block.
// ROUND-3 STRUCTURE: 512 blocks x 256 threads (4 waves), M=8 rows/block,
// __launch_bounds__(256,1). Each wave owns TWO 16-col tiles per gate
// (jj=0,1), so 2 waves cover layer-1 and 2 waves cover layer-0.
// Register demand ~210-230/wave (B1f=128 or B0ar=128 + accums + frags),
// well under the 256-total ceiling for 2 waves/SIMD -> TWO blocks
// co-reside per CU, one wave of each block per SIMD. The two blocks have
// INDEPENDENT barriers: when chain A stalls (ds latency, MFMA chain,
// s_barrier), chain B issues -> absorbs the ~55% per-interval stall
// measured in rounds 0/2.
//   round-1 lesson: (512,4) splits the unified file 64 arch + 64 acc and
//   spills weights to scratch (3.9 GB fetch). round-2 lesson: 8-wave
//   blocks at 128 arch VGPRs never co-schedule (total incl. AGPR > 128),
//   -> 512 blocks serialized as 2 passes of 175us.
// M=8 epilogue: C tile rows 0-7 valid in lanes 0-31; permlane32_swap
// redistributes so each lane runs the LSTM cell for 2 rows per jj-tile
// (4 h/lane total) -> per-SIMD transcendental issue is at the invariant
// floor. Per-row arithmetic identical to the round-0/2 passing kernels.

#define T_ENC 128
#define D_IN 4
#define H 64
#define STEPS 60
#define M 8            // batch rows per block
#define MR 8           // LDS rows; A-frag reads row n16&7 (2-lane broadcast)
#define A0S 104        // halves/row: [x(4) | h0(64) | zero-pad]
#define A1S 136        // halves/row: [h0(64) | h1(64)] + slack
#define XN (M * T_ENC * D_IN)   // 4096 halves
#define NTHREADS 256

typedef _Float16 half8 __attribute__((ext_vector_type(8)));
typedef _Float16 half4_t __attribute__((ext_vector_type(4)));
typedef float float4v __attribute__((ext_vector_type(4)));
typedef unsigned uint2v __attribute__((ext_vector_type(2)));

__device__ __forceinline__ float fast_sigmoid(float x) {
    float e = __builtin_amdgcn_exp2f(-1.44269504f * x);
    return __builtin_amdgcn_rcpf(1.0f + e);
}
__device__ __forceinline__ float fast_tanh(float x) {
    float e = __builtin_amdgcn_exp2f(2.88539008f * x);   // exp(2x)
    return __builtin_fmaf(-2.0f, __builtin_amdgcn_rcpf(e + 1.0f), 1.0f);
}

// v_permlane32_swap_b32: result.x = [a lanes0-31 | b lanes0-31]
__device__ __forceinline__ float take_lo_pair(float a, float b) {
    uint2v r = __builtin_amdgcn_permlane32_swap(
        __builtin_bit_cast(unsigned, a), __builtin_bit_cast(unsigned, b),
        false, false);
    return __builtin_bit_cast(float, r.x);
}

// Redistribute a 16x16 C tile (valid rows 0-7 live in lanes 0-31) so each
// lane handles rows (rowA, rowA+1) at its column, then run the LSTM cell.
// rowA = quad<2 ? 4*quad : 4*(quad-2)+2.  (verified passing in rounds 1-2)
__device__ __forceinline__ void lstm_epi(const float4v C[4], float cs[2],
                                         _Float16* h_a, _Float16* h_b) {
    float ga[4], gb[4];
    #pragma unroll
    for (int tau = 0; tau < 4; ++tau) {
        ga[tau] = take_lo_pair(C[tau][0], C[tau][2]);   // rows {0,4 | 2,6}
        gb[tau] = take_lo_pair(C[tau][1], C[tau][3]);   // rows {1,5 | 3,7}
    }
    {
        const float ig = fast_sigmoid(ga[0]);
        const float fg = fast_sigmoid(ga[1]);
        const float gg = fast_tanh   (ga[2]);
        const float og = fast_sigmoid(ga[3]);
        const float c  = fg * cs[0] + ig * gg;
        cs[0] = c;
        *h_a = (_Float16)(og * fast_tanh(c));
    }
    {
        const float ig = fast_sigmoid(gb[0]);
        const float fg = fast_sigmoid(gb[1]);
        const float gg = fast_tanh   (gb[2]);
        const float og = fast_sigmoid(gb[3]);
        const float c  = fg * cs[1] + ig * gg;
        cs[1] = c;
        *h_b = (_Float16)(og * fast_tanh(c));
    }
}

__global__ __launch_bounds__(NTHREADS, 1) void lstm_ar_kernel(
    const float* __restrict__ x,
    const float* __restrict__ Wih0, const float* __restrict__ Whh0,
    const float* __restrict__ bih0, const float* __restrict__ bhh0,
    const float* __restrict__ Wih1, const float* __restrict__ Whh1,
    const float* __restrict__ bih1, const float* __restrict__ bhh1,
    const float* __restrict__ Wfc,  const float* __restrict__ bfc,
    float* __restrict__ out)
{
    __shared__ __align__(16) _Float16 A0buf[2][MR * A0S];
    __shared__ __align__(16) _Float16 A1buf[2][MR * A1S];
    __shared__ __align__(16) _Float16 xAll[XN];                // [elem][t][d] fp16
    __shared__ __align__(16) float    predsS[M * STEPS * D_IN];

    const int tid  = threadIdx.x;
    const int wave = tid >> 6;         // 0..3
    const int lane = tid & 63;
    const int n16  = lane & 15;
    const int quad = lane >> 4;
    const int grp  = wave >> 1;        // 0: layer-1 waves, 1: layer-0 waves
    const int w2   = wave & 1;         // which 32-col half this wave owns
    const int m0   = blockIdx.x * M;
    const int m    = n16 & 7;          // A-frag row (dup rows 8-15 -> broadcast)
    const int rowA = (quad < 2) ? (quad * 4) : ((quad - 2) * 4 + 2);

    { _Float16* z = &A0buf[0][0]; for (int i = tid; i < 2 * MR * A0S; i += NTHREADS) z[i] = (_Float16)0.f; }
    { _Float16* z = &A1buf[0][0]; for (int i = tid; i < 2 * MR * A1S; i += NTHREADS) z[i] = (_Float16)0.f; }
    // x -> fp16 LDS (one-time; removes all global loads from the main loop)
    for (int j = tid; j < XN / 4; j += NTHREADS) {
        const float4v v = *(const float4v*)&x[(size_t)m0 * T_ENC * D_IN + (size_t)j * 4];
        *(half4_t*)&xAll[j * 4] =
            (half4_t){(_Float16)v[0], (_Float16)v[1], (_Float16)v[2], (_Float16)v[3]};
    }

    // ---- per-wave weight fragments: B[k][n], n = 64*tau + 32*w2 + 16*jj + n16 ----
    half8 B1f[4][4][2];          // grp0: layer1, K=128 = [h0 | h1]   (128 VGPR)
    half8 B0f[3][4][2];          // grp1: encode layer0, K=96         (96 VGPR)
    float b1v[4][2], b0v[4][2], b0arv[4][2];
    if (grp == 0) {
        #pragma unroll
        for (int tau = 0; tau < 4; ++tau)
            #pragma unroll
            for (int jj = 0; jj < 2; ++jj) {
                const int n = 64 * tau + 32 * w2 + 16 * jj + n16;
                b1v[tau][jj] = bih1[n] + bhh1[n];
                #pragma unroll
                for (int kt = 0; kt < 4; ++kt)
                    #pragma unroll
                    for (int j = 0; j < 8; ++j) {
                        const int k = kt * 32 + quad * 8 + j;
                        B1f[kt][tau][jj][j] = (_Float16)((k < H) ? Wih1[n * H + k] : Whh1[n * H + (k - H)]);
                    }
            }
    } else {
        #pragma unroll
        for (int tau = 0; tau < 4; ++tau)
            #pragma unroll
            for (int jj = 0; jj < 2; ++jj) {
                const int n = 64 * tau + 32 * w2 + 16 * jj + n16;
                b0v[tau][jj] = bih0[n] + bhh0[n];
                float wb = 0.f;
                #pragma unroll
                for (int d = 0; d < 4; ++d) wb += Wih0[n * D_IN + d] * bfc[d];
                b0arv[tau][jj] = b0v[tau][jj] + wb;
                #pragma unroll
                for (int kt = 0; kt < 3; ++kt)
                    #pragma unroll
                    for (int j = 0; j < 8; ++j) {
                        const int k = kt * 32 + quad * 8 + j;
                        float v = 0.f;
                        if (k < 4)       v = Wih0[n * D_IN + k];
                        else if (k < 68) v = Whh0[n * H + (k - 4)];
                        B0f[kt][tau][jj][j] = (_Float16)v;
                    }
            }
    }

    float c0s[2][2] = {{0.f, 0.f}, {0.f, 0.f}};   // grp1 state [jj][row]
    float c1s[2][2] = {{0.f, 0.f}, {0.f, 0.f}};   // grp0 state

    __syncthreads();   // LDS zero + xAll ready

    // x(0) -> A0buf[1] x-slot (prologue input); x(1) -> A0buf[0] (iter-0 input)
    if (grp == 1 && w2 == 1 && lane < 8) {
        *(half4_t*)&A0buf[1][lane * A0S] = *(const half4_t*)&xAll[(lane * T_ENC + 0) * D_IN];
        *(half4_t*)&A0buf[0][lane * A0S] = *(const half4_t*)&xAll[(lane * T_ENC + 1) * D_IN];
    }
    __syncthreads();

    // ---- prologue: L0 step 0 (grp1 only) ----
    if (grp == 1) {
        half8 a0f[3];
        #pragma unroll
        for (int kt = 0; kt < 3; ++kt)
            a0f[kt] = *(const half8*)&A0buf[1][m * A0S + kt * 32 + quad * 8];
        float4v C0[2][4];
        #pragma unroll
        for (int jj = 0; jj < 2; ++jj)
            #pragma unroll
            for (int tau = 0; tau < 4; ++tau)
                C0[jj][tau] = (float4v){b0v[tau][jj], b0v[tau][jj], b0v[tau][jj], b0v[tau][jj]};
        #pragma unroll
        for (int kt = 0; kt < 3; ++kt)
            #pragma unroll
            for (int tau = 0; tau < 4; ++tau)
                #pragma unroll
                for (int jj = 0; jj < 2; ++jj)
                    C0[jj][tau] = __builtin_amdgcn_mfma_f32_16x16x32_f16(a0f[kt], B0f[kt][tau][jj], C0[jj][tau], 0, 0, 0);
        #pragma unroll
        for (int jj = 0; jj < 2; ++jj) {
            const int jcol = 32 * w2 + 16 * jj + n16;
            _Float16 ha, hb;
            lstm_epi(C0[jj], c0s[jj], &ha, &hb);
            A1buf[0][rowA * A1S + jcol]           = ha;
            A1buf[0][(rowA + 1) * A1S + jcol]     = hb;
            A0buf[0][rowA * A0S + 4 + jcol]       = ha;
            A0buf[0][(rowA + 1) * A0S + 4 + jcol] = hb;
        }
    }
    __syncthreads();

    // ---- encode: iter t = L1(t) on grp0  ||  L0(t+1) on grp1; 1 barrier ----
    for (int t = 0; t < T_ENC; ++t) {
        const int p = t & 1;
        if (grp == 0) {
            const _Float16* cur1 = &A1buf[p][0];
            _Float16* nxt1 = &A1buf[1 - p][0];
            half8 a1f[4];
            #pragma unroll
            for (int kt = 0; kt < 4; ++kt)
                a1f[kt] = *(const half8*)&cur1[m * A1S + kt * 32 + quad * 8];
            float4v C1[2][4];
            #pragma unroll
            for (int jj = 0; jj < 2; ++jj)
                #pragma unroll
                for (int tau = 0; tau < 4; ++tau)
                    C1[jj][tau] = (float4v){b1v[tau][jj], b1v[tau][jj], b1v[tau][jj], b1v[tau][jj]};
            #pragma unroll
            for (int kt = 0; kt < 4; ++kt)
                #pragma unroll
                for (int tau = 0; tau < 4; ++tau)
                    #pragma unroll
                    for (int jj = 0; jj < 2; ++jj)
                        C1[jj][tau] = __builtin_amdgcn_mfma_f32_16x16x32_f16(a1f[kt], B1f[kt][tau][jj], C1[jj][tau], 0, 0, 0);
            #pragma unroll
            for (int jj = 0; jj < 2; ++jj) {
                const int jcol = 32 * w2 + 16 * jj + n16;
                _Float16 ha, hb;
                lstm_epi(C1[jj], c1s[jj], &ha, &hb);
                nxt1[rowA * A1S + 64 + jcol]       = ha;
                nxt1[(rowA + 1) * A1S + 64 + jcol] = hb;
            }
        } else {
            const _Float16* cur0 = &A0buf[p][0];
            _Float16* nxt0 = &A0buf[1 - p][0];
            _Float16* nxt1 = &A1buf[1 - p][0];
            half8 a0f[3];
            #pragma unroll
            for (int kt = 0; kt < 3; ++kt)
                a0f[kt] = *(const half8*)&cur0[m * A0S + kt * 32 + quad * 8];
            float4v C0[2][4];
            #pragma unroll
            for (int jj = 0; jj < 2; ++jj)
                #pragma unroll
                for (int tau = 0; tau < 4; ++tau)
                    C0[jj][tau] = (float4v){b0v[tau][jj], b0v[tau][jj], b0v[tau][jj], b0v[tau][jj]};
            #pragma unroll
            for (int kt = 0; kt < 3; ++kt)
                #pragma unroll
                for (int tau = 0; tau < 4; ++tau)
                    #pragma unroll
                    for (int jj = 0; jj < 2; ++jj)
                        C0[jj][tau] = __builtin_amdgcn_mfma_f32_16x16x32_f16(a0f[kt], B0f[kt][tau][jj], C0[jj][tau], 0, 0, 0);
            #pragma unroll
            for (int jj = 0; jj < 2; ++jj) {
                const int jcol = 32 * w2 + 16 * jj + n16;
                _Float16 ha, hb;
                lstm_epi(C0[jj], c0s[jj], &ha, &hb);
                nxt1[rowA * A1S + jcol]           = ha;
                nxt1[(rowA + 1) * A1S + jcol]     = hb;
                nxt0[rowA * A0S + 4 + jcol]       = ha;
                nxt0[(rowA + 1) * A0S + 4 + jcol] = hb;
            }
            if (w2 == 1 && lane < 8) {         // x(t+2) -> nxt0 x-slot
                int tn = t + 2; if (tn > T_ENC - 1) tn = T_ENC - 1;
                *(half4_t*)&nxt0[lane * A0S] = *(const half4_t*)&xAll[(lane * T_ENC + tn) * D_IN];
            }
        }
        __syncthreads();
    }

    // ---- AR weights: grp1 swaps B0f -> B0ar = [Whh0 | Wih0@Wfc]; Bfc on wave grp1/w2==0 ----
    half8 B0ar[4][4][2];
    half8 Bfc[2];
    float bfcv = 0.f;
    if (grp == 1) {
        #pragma unroll
        for (int tau = 0; tau < 4; ++tau)
            #pragma unroll
            for (int jj = 0; jj < 2; ++jj) {
                const int n = 64 * tau + 32 * w2 + 16 * jj + n16;
                #pragma unroll
                for (int kt = 0; kt < 4; ++kt)
                    #pragma unroll
                    for (int j = 0; j < 8; ++j) {
                        const int k = kt * 32 + quad * 8 + j;
                        float v;
                        if (k < H) v = Whh0[n * H + k];
                        else {
                            const int c = k - H;
                            v = Wih0[n * D_IN + 0] * Wfc[0 * H + c] + Wih0[n * D_IN + 1] * Wfc[1 * H + c]
                              + Wih0[n * D_IN + 2] * Wfc[2 * H + c] + Wih0[n * D_IN + 3] * Wfc[3 * H + c];
                        }
                        B0ar[kt][tau][jj][j] = (_Float16)v;
                    }
            }
        if (w2 == 0) {
            #pragma unroll
            for (int kt = 0; kt < 2; ++kt)
                #pragma unroll
                for (int j = 0; j < 8; ++j) {
                    const int k = kt * 32 + quad * 8 + j;
                    Bfc[kt][j] = (_Float16)((n16 < 4) ? Wfc[n16 * H + k] : 0.f);
                }
            if (n16 < 4) bfcv = bfc[n16];
        }
    }
    // grp0 overlaps: C1pre(0) = b1 + Whh1 · h1(127)
    float4v C1pre[2][4];
    if (grp == 0) {
        half8 ah[2];
        #pragma unroll
        for (int kt = 0; kt < 2; ++kt)
            ah[kt] = *(const half8*)&A1buf[0][m * A1S + 64 + kt * 32 + quad * 8];
        #pragma unroll
        for (int jj = 0; jj < 2; ++jj)
            #pragma unroll
            for (int tau = 0; tau < 4; ++tau)
                C1pre[jj][tau] = (float4v){b1v[tau][jj], b1v[tau][jj], b1v[tau][jj], b1v[tau][jj]};
        #pragma unroll
        for (int kt = 0; kt < 2; ++kt)
            #pragma unroll
            for (int tau = 0; tau < 4; ++tau)
                #pragma unroll
                for (int jj = 0; jj < 2; ++jj)
                    C1pre[jj][tau] = __builtin_amdgcn_mfma_f32_16x16x32_f16(ah[kt], B1f[2 + kt][tau][jj], C1pre[jj][tau], 0, 0, 0);
    }

    // ---- AR: phase1 = L1 finish (grp0) || Whh0-pre (grp1); B1;
    //          phase2 = L0ar finish + head (grp1) || Whh1-pre (grp0); B2 ----
    for (int s = 0; s < STEPS; ++s) {
        const int q = s & 1;
        const _Float16* cur = &A1buf[q][0];
        _Float16* nxt = &A1buf[1 - q][0];

        half8 ah0[2];   // h0(s)
        #pragma unroll
        for (int kt = 0; kt < 2; ++kt)
            ah0[kt] = *(const half8*)&cur[m * A1S + kt * 32 + quad * 8];

        float4v C0pre[2][4];
        if (grp == 0) {
            float4v C1[2][4];
            #pragma unroll
            for (int jj = 0; jj < 2; ++jj)
                #pragma unroll
                for (int tau = 0; tau < 4; ++tau)
                    C1[jj][tau] = C1pre[jj][tau];
            #pragma unroll
            for (int kt = 0; kt < 2; ++kt)
                #pragma unroll
                for (int tau = 0; tau < 4; ++tau)
                    #pragma unroll
                    for (int jj = 0; jj < 2; ++jj)
                        C1[jj][tau] = __builtin_amdgcn_mfma_f32_16x16x32_f16(ah0[kt], B1f[kt][tau][jj], C1[jj][tau], 0, 0, 0);
            #pragma unroll
            for (int jj = 0; jj < 2; ++jj) {
                const int jcol = 32 * w2 + 16 * jj + n16;
                _Float16 ha, hb;
                lstm_epi(C1[jj], c1s[jj], &ha, &hb);
                nxt[rowA * A1S + 64 + jcol]       = ha;
                nxt[(rowA + 1) * A1S + 64 + jcol] = hb;
            }
        } else {
            #pragma unroll
            for (int jj = 0; jj < 2; ++jj)
                #pragma unroll
                for (int tau = 0; tau < 4; ++tau)
                    C0pre[jj][tau] = (float4v){b0arv[tau][jj], b0arv[tau][jj], b0arv[tau][jj], b0arv[tau][jj]};
            #pragma unroll
            for (int kt = 0; kt < 2; ++kt)
                #pragma unroll
                for (int tau = 0; tau < 4; ++tau)
                    #pragma unroll
                    for (int jj = 0; jj < 2; ++jj)
                        C0pre[jj][tau] = __builtin_amdgcn_mfma_f32_16x16x32_f16(ah0[kt], B0ar[kt][tau][jj], C0pre[jj][tau], 0, 0, 0);
        }
        __syncthreads();   // B1: h1(s) visible

        half8 ah1[2];   // h1(s)
        #pragma unroll
        for (int kt = 0; kt < 2; ++kt)
            ah1[kt] = *(const half8*)&nxt[m * A1S + 64 + kt * 32 + quad * 8];

        if (grp == 1) {
            float4v C0[2][4];
            #pragma unroll
            for (int jj = 0; jj < 2; ++jj)
                #pragma unroll
                for (int tau = 0; tau < 4; ++tau)
                    C0[jj][tau] = C0pre[jj][tau];
            #pragma unroll
            for (int kt = 0; kt < 2; ++kt)
                #pragma unroll
                for (int tau = 0; tau < 4; ++tau)
                    #pragma unroll
                    for (int jj = 0; jj < 2; ++jj)
                        C0[jj][tau] = __builtin_amdgcn_mfma_f32_16x16x32_f16(ah1[kt], B0ar[2 + kt][tau][jj], C0[jj][tau], 0, 0, 0);
            if (w2 == 0) {   // head: pred(s) = Wfc·h1(s)+bfc, off critical path
                float4v Cp = (float4v){bfcv, bfcv, bfcv, bfcv};
                Cp = __builtin_amdgcn_mfma_f32_16x16x32_f16(ah1[0], Bfc[0], Cp, 0, 0, 0);
                Cp = __builtin_amdgcn_mfma_f32_16x16x32_f16(ah1[1], Bfc[1], Cp, 0, 0, 0);
                if (n16 < 4 && quad < 2) {     // valid rows 0-7 live in quads 0-1
                    #pragma unroll
                    for (int r = 0; r < 4; ++r)
                        predsS[(quad * 4 + r) * (STEPS * D_IN) + s * D_IN + n16] = Cp[r];
                }
            }
            #pragma unroll
            for (int jj = 0; jj < 2; ++jj) {
                const int jcol = 32 * w2 + 16 * jj + n16;
                _Float16 ha, hb;
                lstm_epi(C0[jj], c0s[jj], &ha, &hb);
                nxt[rowA * A1S + jcol]           = ha;
                nxt[(rowA + 1) * A1S + jcol]     = hb;
            }
        } else {   // grp0 pre-computes C1pre(s+1) = b1 + Whh1·h1(s)
            #pragma unroll
            for (int jj = 0; jj < 2; ++jj)
                #pragma unroll
                for (int tau = 0; tau < 4; ++tau)
                    C1pre[jj][tau] = (float4v){b1v[tau][jj], b1v[tau][jj], b1v[tau][jj], b1v[tau][jj]};
            #pragma unroll
            for (int kt = 0; kt < 2; ++kt)
                #pragma unroll
                for (int tau = 0; tau < 4; ++tau)
                    #pragma unroll
                    for (int jj = 0; jj < 2; ++jj)
                        C1pre[jj][tau] = __builtin_amdgcn_mfma_f32_16x16x32_f16(ah1[kt], B1f[2 + kt][tau][jj], C1pre[jj][tau], 0, 0, 0);
        }
        __syncthreads();   // B2: h0(s+1) visible
    }

    // ---- bulk store preds ----
    for (int j = tid; j < M * STEPS; j += NTHREADS) {
        const int elem = j / STEPS, r = j - elem * STEPS;
        ((float4v*)out)[(size_t)(m0 + elem) * STEPS + r] = ((const float4v*)predsS)[j];
    }
}

extern "C" void kernel_launch(void* const* d_in, const int* in_sizes, int n_in,
                              void* d_out, int out_size, void* d_ws, size_t ws_size,
                              hipStream_t stream) {
    const float* x    = (const float*)d_in[0];
    const float* Wih0 = (const float*)d_in[1];
    const float* Whh0 = (const float*)d_in[2];
    const float* bih0 = (const float*)d_in[3];
    const float* bhh0 = (const float*)d_in[4];
    const float* Wih1 = (const float*)d_in[5];
    const float* Whh1 = (const float*)d_in[6];
    const float* bih1 = (const float*)d_in[7];
    const float* bhh1 = (const float*)d_in[8];
    const float* Wfc  = (const float*)d_in[9];
    const float* bfc  = (const float*)d_in[10];
    float* out = (float*)d_out;

    dim3 grid(4096 / M);     // 512 blocks -> 2 per CU (independent barriers)
    dim3 block(NTHREADS);    // 4 waves -> 1 wave/SIMD/block; 2 waves/SIMD total
    lstm_ar_kernel<<<grid, block, 0, stream>>>(
        x, Wih0, Whh0, bih0, bhh0, Wih1, Whh1, bih1, bhh1, Wfc, bfc, out);
}

// Round 4
// 357.475 us; speedup vs baseline: 1.3921x; 1.3921x over previous
//
#include <hip/hip_runtime.h>

// 2-layer LSTM (H=64) encode(128) + AR(60), B=4096, persistent per-block.
// ROUND-4 STRUCTURE: 256 blocks x 1024 threads (16 waves), M_BLK=16 rows,
// organized as TWO independent 8-row chains (waves 0-7: rows 0-7,
// waves 8-15: rows 8-15), each chain = the verified round-2 M=8 layout
// (4 L1 waves + 4 L0 waves, permlane epilogue, 2 cells/lane).
// Wave->SIMD mapping (wave%4) puts {c0L1, c0L0, c1L1, c1L0} on each SIMD:
// 4 independent instruction streams/SIMD -> ds/MFMA/trans latency of one
// stream hides under the issue of the others. 16 waves/CU forces a
// 128-total-reg/wave cap, met via STATIC REGISTER SHARING (the round 0-3
// lesson: the allocator reserves the UNION of divergent per-role arrays):
//   - ONE Bw[4][4] weight array: grp0 = L1 weights; grp1 = L0-encode
//     weights, rewritten in place to [Whh0 | Wih0@Wfc] at the AR switch.
//   - ONE bias[4]: grp1 adds Wih0·bfc in place at the AR switch.
//   - ONE Cpre[4] accumulator carried across both AR phases (no copy):
//     grp0 accumulates phase2->phase1, grp1 phase1->phase2.
// Per-row arithmetic identical to the round-0..3 passing kernels.

#define T_ENC 128
#define D_IN 4
#define H 64
#define STEPS 60
#define M_BLK 16       // batch rows per block
#define M 8            // rows per chain
#define MR 8           // LDS rows per chain buffer
#define A0S 104        // halves/row: [x(4) | h0(64) | zero-pad]
#define A1S 136        // halves/row: [h0(64) | h1(64)] + slack
#define A0P (MR * A0S)
#define A1P (MR * A1S)
#define XN (M_BLK * T_ENC * D_IN)   // 8192 halves
#define NTHREADS 1024

typedef _Float16 half8 __attribute__((ext_vector_type(8)));
typedef _Float16 half4_t __attribute__((ext_vector_type(4)));
typedef float float4v __attribute__((ext_vector_type(4)));
typedef unsigned uint2v __attribute__((ext_vector_type(2)));

__device__ __forceinline__ float fast_sigmoid(float x) {
    float e = __builtin_amdgcn_exp2f(-1.44269504f * x);
    return __builtin_amdgcn_rcpf(1.0f + e);
}
__device__ __forceinline__ float fast_tanh(float x) {
    float e = __builtin_amdgcn_exp2f(2.88539008f * x);   // exp(2x)
    return __builtin_fmaf(-2.0f, __builtin_amdgcn_rcpf(e + 1.0f), 1.0f);
}

// v_permlane32_swap_b32: result.x = [a lanes0-31 | b lanes0-31]
__device__ __forceinline__ float take_lo_pair(float a, float b) {
    uint2v r = __builtin_amdgcn_permlane32_swap(
        __builtin_bit_cast(unsigned, a), __builtin_bit_cast(unsigned, b),
        false, false);
    return __builtin_bit_cast(float, r.x);
}

// Redistribute a 16x16 C tile (valid rows 0-7 live in lanes 0-31) so each
// lane handles rows (rowA, rowA+1) at its column, then run the LSTM cell.
// rowA = quad<2 ? 4*quad : 4*(quad-2)+2.  (verified passing, rounds 1-3)
__device__ __forceinline__ void lstm_epi(const float4v C[4], float cs[2],
                                         _Float16* h_a, _Float16* h_b) {
    float ga[4], gb[4];
    #pragma unroll
    for (int tau = 0; tau < 4; ++tau) {
        ga[tau] = take_lo_pair(C[tau][0], C[tau][2]);   // rows {0,4 | 2,6}
        gb[tau] = take_lo_pair(C[tau][1], C[tau][3]);   // rows {1,5 | 3,7}
    }
    {
        const float ig = fast_sigmoid(ga[0]);
        const float fg = fast_sigmoid(ga[1]);
        const float gg = fast_tanh   (ga[2]);
        const float og = fast_sigmoid(ga[3]);
        const float c  = fg * cs[0] + ig * gg;
        cs[0] = c;
        *h_a = (_Float16)(og * fast_tanh(c));
    }
    {
        const float ig = fast_sigmoid(gb[0]);
        const float fg = fast_sigmoid(gb[1]);
        const float gg = fast_tanh   (gb[2]);
        const float og = fast_sigmoid(gb[3]);
        const float c  = fg * cs[1] + ig * gg;
        cs[1] = c;
        *h_b = (_Float16)(og * fast_tanh(c));
    }
}

__global__ __launch_bounds__(NTHREADS, 1) void lstm_ar_kernel(
    const float* __restrict__ x,
    const float* __restrict__ Wih0, const float* __restrict__ Whh0,
    const float* __restrict__ bih0, const float* __restrict__ bhh0,
    const float* __restrict__ Wih1, const float* __restrict__ Whh1,
    const float* __restrict__ bih1, const float* __restrict__ bhh1,
    const float* __restrict__ Wfc,  const float* __restrict__ bfc,
    float* __restrict__ out)
{
    __shared__ __align__(16) _Float16 A0buf[2][2 * A0P];   // [chain][pp*A0P]
    __shared__ __align__(16) _Float16 A1buf[2][2 * A1P];   // [chain][pp*A1P]
    __shared__ __align__(16) _Float16 xAll[XN];            // [elem][t][d] fp16
    __shared__ __align__(16) float    predsS[M_BLK * STEPS * D_IN];

    const int tid   = threadIdx.x;
    const int wave  = tid >> 6;        // 0..15
    const int lane  = tid & 63;
    const int n16   = lane & 15;
    const int quad  = lane >> 4;
    const int chain = wave >> 3;       // 0: rows 0-7, 1: rows 8-15
    const int grp   = (wave >> 2) & 1; // 0: layer-1 wave, 1: layer-0 wave
    const int w4    = wave & 3;        // colgroup; also the SIMD id
    const int m0    = blockIdx.x * M_BLK;
    const int m     = n16 & 7;         // A-frag row (rows 8-15 dup -> broadcast)
    const int jcol  = 16 * w4 + n16;   // hidden column owned in epilogues
    const int rowA  = (quad < 2) ? (quad * 4) : ((quad - 2) * 4 + 2);

    _Float16* A0 = &A0buf[chain][0];
    _Float16* A1 = &A1buf[chain][0];

    { _Float16* z = &A0buf[0][0]; for (int i = tid; i < 2 * 2 * A0P; i += NTHREADS) z[i] = (_Float16)0.f; }
    { _Float16* z = &A1buf[0][0]; for (int i = tid; i < 2 * 2 * A1P; i += NTHREADS) z[i] = (_Float16)0.f; }
    // x -> fp16 LDS (one-time; removes all global loads from the main loop)
    for (int j = tid; j < XN / 4; j += NTHREADS) {
        const float4v v = *(const float4v*)&x[(size_t)m0 * T_ENC * D_IN + (size_t)j * 4];
        *(half4_t*)&xAll[j * 4] =
            (half4_t){(_Float16)v[0], (_Float16)v[1], (_Float16)v[2], (_Float16)v[3]};
    }

    // ---- SHARED weight fragments: Bw[k][n], n = 64*tau + jcol ----
    // grp0: layer1, K=128 = [h0 | h1] (4 kt).  grp1: layer0 encode, K=96 (3 kt).
    half8 Bw[4][4];
    half8 Bfc[2];
    float bias[4];
    float bfcv = 0.f;
    if (grp == 0) {
        #pragma unroll
        for (int tau = 0; tau < 4; ++tau) {
            const int n = 64 * tau + jcol;
            bias[tau] = bih1[n] + bhh1[n];
            #pragma unroll
            for (int kt = 0; kt < 4; ++kt)
                #pragma unroll
                for (int j = 0; j < 8; ++j) {
                    const int k = kt * 32 + quad * 8 + j;
                    Bw[kt][tau][j] = (_Float16)((k < H) ? Wih1[n * H + k] : Whh1[n * H + (k - H)]);
                }
        }
    } else {
        #pragma unroll
        for (int tau = 0; tau < 4; ++tau) {
            const int n = 64 * tau + jcol;
            bias[tau] = bih0[n] + bhh0[n];
            #pragma unroll
            for (int kt = 0; kt < 3; ++kt)
                #pragma unroll
                for (int j = 0; j < 8; ++j) {
                    const int k = kt * 32 + quad * 8 + j;
                    float v = 0.f;
                    if (k < 4)       v = Wih0[n * D_IN + k];
                    else if (k < 68) v = Whh0[n * H + (k - 4)];
                    Bw[kt][tau][j] = (_Float16)v;
                }
        }
    }

    float cs[2] = {0.f, 0.f};   // cell state for rows (rowA, rowA+1) @ jcol

    __syncthreads();   // LDS zero + xAll ready

    // x(0) -> A0[pp=1] x-slot (prologue input); x(1) -> A0[pp=0] (iter-0 input)
    if (grp == 1 && w4 == 2 && lane < 8) {
        const int elem = chain * 8 + lane;
        *(half4_t*)&A0[A0P + lane * A0S] = *(const half4_t*)&xAll[(elem * T_ENC + 0) * D_IN];
        *(half4_t*)&A0[lane * A0S]       = *(const half4_t*)&xAll[(elem * T_ENC + 1) * D_IN];
    }
    __syncthreads();

    // ---- prologue: L0 step 0 (grp1 only) ----
    if (grp == 1) {
        half8 af[3];
        #pragma unroll
        for (int kt = 0; kt < 3; ++kt)
            af[kt] = *(const half8*)&A0[A0P + m * A0S + kt * 32 + quad * 8];
        float4v C[4];
        #pragma unroll
        for (int tau = 0; tau < 4; ++tau)
            C[tau] = (float4v){bias[tau], bias[tau], bias[tau], bias[tau]};
        #pragma unroll
        for (int kt = 0; kt < 3; ++kt)
            #pragma unroll
            for (int tau = 0; tau < 4; ++tau)
                C[tau] = __builtin_amdgcn_mfma_f32_16x16x32_f16(af[kt], Bw[kt][tau], C[tau], 0, 0, 0);
        _Float16 ha, hb;
        lstm_epi(C, cs, &ha, &hb);
        A1[rowA * A1S + jcol]           = ha;
        A1[(rowA + 1) * A1S + jcol]     = hb;
        A0[rowA * A0S + 4 + jcol]       = ha;
        A0[(rowA + 1) * A0S + 4 + jcol] = hb;
    }
    __syncthreads();

    // ---- encode: iter t = L1(t) on grp0  ||  L0(t+1) on grp1; 1 barrier ----
    for (int t = 0; t < T_ENC; ++t) {
        const int p = t & 1;
        if (grp == 0) {
            const _Float16* cur1 = A1 + p * A1P;
            _Float16* nxt1 = A1 + (1 - p) * A1P;
            half8 af[4];
            #pragma unroll
            for (int kt = 0; kt < 4; ++kt)
                af[kt] = *(const half8*)&cur1[m * A1S + kt * 32 + quad * 8];
            float4v C[4];
            #pragma unroll
            for (int tau = 0; tau < 4; ++tau)
                C[tau] = (float4v){bias[tau], bias[tau], bias[tau], bias[tau]};
            #pragma unroll
            for (int kt = 0; kt < 4; ++kt)
                #pragma unroll
                for (int tau = 0; tau < 4; ++tau)
                    C[tau] = __builtin_amdgcn_mfma_f32_16x16x32_f16(af[kt], Bw[kt][tau], C[tau], 0, 0, 0);
            _Float16 ha, hb;
            lstm_epi(C, cs, &ha, &hb);
            nxt1[rowA * A1S + 64 + jcol]       = ha;
            nxt1[(rowA + 1) * A1S + 64 + jcol] = hb;
        } else {
            const _Float16* cur0 = A0 + p * A0P;
            _Float16* nxt0 = A0 + (1 - p) * A0P;
            _Float16* nxt1 = A1 + (1 - p) * A1P;
            half8 af[3];
            #pragma unroll
            for (int kt = 0; kt < 3; ++kt)
                af[kt] = *(const half8*)&cur0[m * A0S + kt * 32 + quad * 8];
            float4v C[4];
            #pragma unroll
            for (int tau = 0; tau < 4; ++tau)
                C[tau] = (float4v){bias[tau], bias[tau], bias[tau], bias[tau]};
            #pragma unroll
            for (int kt = 0; kt < 3; ++kt)
                #pragma unroll
                for (int tau = 0; tau < 4; ++tau)
                    C[tau] = __builtin_amdgcn_mfma_f32_16x16x32_f16(af[kt], Bw[kt][tau], C[tau], 0, 0, 0);
            _Float16 ha, hb;
            lstm_epi(C, cs, &ha, &hb);
            nxt1[rowA * A1S + jcol]           = ha;
            nxt1[(rowA + 1) * A1S + jcol]     = hb;
            nxt0[rowA * A0S + 4 + jcol]       = ha;
            nxt0[(rowA + 1) * A0S + 4 + jcol] = hb;
            if (w4 == 2 && lane < 8) {         // x(t+2) -> nxt0 x-slot
                int tn = t + 2; if (tn > T_ENC - 1) tn = T_ENC - 1;
                *(half4_t*)&nxt0[lane * A0S] =
                    *(const half4_t*)&xAll[((chain * 8 + lane) * T_ENC + tn) * D_IN];
            }
        }
        __syncthreads();
    }

    // ---- AR switch: grp1 REWRITES Bw in place -> [Whh0 | Wih0@Wfc],
    //      bias += Wih0·bfc; Bfc on the grp1/w4==0 wave of each chain ----
    if (grp == 1) {
        #pragma unroll
        for (int tau = 0; tau < 4; ++tau) {
            const int n = 64 * tau + jcol;
            float wb = 0.f;
            #pragma unroll
            for (int d = 0; d < 4; ++d) wb += Wih0[n * D_IN + d] * bfc[d];
            bias[tau] += wb;
            #pragma unroll
            for (int kt = 0; kt < 4; ++kt)
                #pragma unroll
                for (int j = 0; j < 8; ++j) {
                    const int k = kt * 32 + quad * 8 + j;
                    float v;
                    if (k < H) v = Whh0[n * H + k];
                    else {
                        const int c = k - H;
                        v = Wih0[n * D_IN + 0] * Wfc[0 * H + c] + Wih0[n * D_IN + 1] * Wfc[1 * H + c]
                          + Wih0[n * D_IN + 2] * Wfc[2 * H + c] + Wih0[n * D_IN + 3] * Wfc[3 * H + c];
                    }
                    Bw[kt][tau][j] = (_Float16)v;
                }
        }
        if (w4 == 0) {
            #pragma unroll
            for (int kt = 0; kt < 2; ++kt)
                #pragma unroll
                for (int j = 0; j < 8; ++j) {
                    const int k = kt * 32 + quad * 8 + j;
                    Bfc[kt][j] = (_Float16)((n16 < 4) ? Wfc[n16 * H + k] : 0.f);
                }
            if (n16 < 4) bfcv = bfc[n16];
        }
    }
    // ONE shared Cpre accumulator across both AR phases (grp0: ph2->ph1;
    // grp1: ph1->ph2). grp0 prologue: Cpre = b1 + Whh1·h1(127).
    float4v Cpre[4];
    if (grp == 0) {
        half8 ah[2];
        #pragma unroll
        for (int kt = 0; kt < 2; ++kt)
            ah[kt] = *(const half8*)&A1[m * A1S + 64 + kt * 32 + quad * 8];
        #pragma unroll
        for (int tau = 0; tau < 4; ++tau)
            Cpre[tau] = (float4v){bias[tau], bias[tau], bias[tau], bias[tau]};
        #pragma unroll
        for (int kt = 0; kt < 2; ++kt)
            #pragma unroll
            for (int tau = 0; tau < 4; ++tau)
                Cpre[tau] = __builtin_amdgcn_mfma_f32_16x16x32_f16(ah[kt], Bw[2 + kt][tau], Cpre[tau], 0, 0, 0);
    }

    // ---- AR: phase1 = L1 finish (grp0) || Whh0-part (grp1); B1;
    //          phase2 = L0ar finish + head (grp1) || Whh1-part (grp0); B2 ----
    for (int s = 0; s < STEPS; ++s) {
        const int q = s & 1;
        const _Float16* cur = A1 + q * A1P;
        _Float16* nxt = A1 + (1 - q) * A1P;

        {
            half8 ah0[2];   // h0(s)
            #pragma unroll
            for (int kt = 0; kt < 2; ++kt)
                ah0[kt] = *(const half8*)&cur[m * A1S + kt * 32 + quad * 8];

            if (grp == 0) {
                #pragma unroll
                for (int kt = 0; kt < 2; ++kt)
                    #pragma unroll
                    for (int tau = 0; tau < 4; ++tau)
                        Cpre[tau] = __builtin_amdgcn_mfma_f32_16x16x32_f16(ah0[kt], Bw[kt][tau], Cpre[tau], 0, 0, 0);
                _Float16 ha, hb;
                lstm_epi(Cpre, cs, &ha, &hb);
                nxt[rowA * A1S + 64 + jcol]       = ha;
                nxt[(rowA + 1) * A1S + 64 + jcol] = hb;
            } else {
                #pragma unroll
                for (int tau = 0; tau < 4; ++tau)
                    Cpre[tau] = (float4v){bias[tau], bias[tau], bias[tau], bias[tau]};
                #pragma unroll
                for (int kt = 0; kt < 2; ++kt)
                    #pragma unroll
                    for (int tau = 0; tau < 4; ++tau)
                        Cpre[tau] = __builtin_amdgcn_mfma_f32_16x16x32_f16(ah0[kt], Bw[kt][tau], Cpre[tau], 0, 0, 0);
            }
        }
        __syncthreads();   // B1: h1(s) visible

        {
            half8 ah1[2];   // h1(s)
            #pragma unroll
            for (int kt = 0; kt < 2; ++kt)
                ah1[kt] = *(const half8*)&nxt[m * A1S + 64 + kt * 32 + quad * 8];

            if (grp == 1) {
                #pragma unroll
                for (int kt = 0; kt < 2; ++kt)
                    #pragma unroll
                    for (int tau = 0; tau < 4; ++tau)
                        Cpre[tau] = __builtin_amdgcn_mfma_f32_16x16x32_f16(ah1[kt], Bw[2 + kt][tau], Cpre[tau], 0, 0, 0);
                if (w4 == 0) {   // head: pred(s) = Wfc·h1(s)+bfc, off critical path
                    float4v Cp = (float4v){bfcv, bfcv, bfcv, bfcv};
                    Cp = __builtin_amdgcn_mfma_f32_16x16x32_f16(ah1[0], Bfc[0], Cp, 0, 0, 0);
                    Cp = __builtin_amdgcn_mfma_f32_16x16x32_f16(ah1[1], Bfc[1], Cp, 0, 0, 0);
                    if (n16 < 4 && quad < 2) {     // valid rows 0-7 live in quads 0-1
                        #pragma unroll
                        for (int r = 0; r < 4; ++r)
                            predsS[(chain * 8 + quad * 4 + r) * (STEPS * D_IN) + s * D_IN + n16] = Cp[r];
                    }
                }
                _Float16 ha, hb;
                lstm_epi(Cpre, cs, &ha, &hb);
                nxt[rowA * A1S + jcol]           = ha;
                nxt[(rowA + 1) * A1S + jcol]     = hb;
            } else {   // grp0 pre-computes Cpre(s+1) = b1 + Whh1·h1(s)
                #pragma unroll
                for (int tau = 0; tau < 4; ++tau)
                    Cpre[tau] = (float4v){bias[tau], bias[tau], bias[tau], bias[tau]};
                #pragma unroll
                for (int kt = 0; kt < 2; ++kt)
                    #pragma unroll
                    for (int tau = 0; tau < 4; ++tau)
                        Cpre[tau] = __builtin_amdgcn_mfma_f32_16x16x32_f16(ah1[kt], Bw[2 + kt][tau], Cpre[tau], 0, 0, 0);
            }
        }
        __syncthreads();   // B2: h0(s+1) visible
    }

    // ---- bulk store preds ----
    for (int j = tid; j < M_BLK * STEPS; j += NTHREADS) {
        const int elem = j / STEPS, r = j - elem * STEPS;
        ((float4v*)out)[(size_t)(m0 + elem) * STEPS + r] = ((const float4v*)predsS)[j];
    }
}

extern "C" void kernel_launch(void* const* d_in, const int* in_sizes, int n_in,
                              void* d_out, int out_size, void* d_ws, size_t ws_size,
                              hipStream_t stream) {
    const float* x    = (const float*)d_in[0];
    const float* Wih0 = (const float*)d_in[1];
    const float* Whh0 = (const float*)d_in[2];
    const float* bih0 = (const float*)d_in[3];
    const float* bhh0 = (const float*)d_in[4];
    const float* Wih1 = (const float*)d_in[5];
    const float* Whh1 = (const float*)d_in[6];
    const float* bih1 = (const float*)d_in[7];
    const float* bhh1 = (const float*)d_in[8];
    const float* Wfc  = (const float*)d_in[9];
    const float* bfc  = (const float*)d_in[10];
    float* out = (float*)d_out;

    dim3 grid(4096 / M_BLK);   // 256 blocks, one per CU
    dim3 block(NTHREADS);      // 16 waves = 4/SIMD: {c0L1,c0L0,c1L1,c1L0}
    lstm_ar_kernel<<<grid, block, 0, stream>>>(
        x, Wih0, Whh0, bih0, bhh0, Wih1, Whh1, bih1, bhh1, Wfc, bfc, out);
}